// Round 7
// baseline (3243.585 us; speedup 1.0000x reference)
//
#include <hip/hip_runtime.h>
#include <hip/hip_bf16.h>
#include <stdint.h>

typedef __bf16 bf16;
typedef bf16 bf16x8 __attribute__((ext_vector_type(8)));
typedef float f32x4 __attribute__((ext_vector_type(4)));

// Load 8 consecutive elements as a bf16x8 MFMA operand pack.
__device__ __forceinline__ bf16x8 load8(const float* p) {
    const f32x4 lo = *(const f32x4*)p;
    const f32x4 hi = *(const f32x4*)(p + 4);
    bf16x8 v;
#pragma unroll
    for (int r = 0; r < 4; ++r) { v[r] = (bf16)lo[r]; v[4 + r] = (bf16)hi[r]; }
    return v;
}
__device__ __forceinline__ bf16x8 load8(const bf16* p) {
    return *(const bf16x8*)p;
}

// ---------------------------------------------------------------------------
// C[M,N] = A[M,K] @ B[N,K]^T   (fp32 accum; AT/BT in {float,bf16}; CT out)
// 128x128 tile, BK=32, 4 waves, each wave 64x64 (4x4 MFMAs). Register staging.
// (MFMA path validated: bit-matched naive fp32 GEMM in round-6 bisect.)
// ---------------------------------------------------------------------------
template <typename AT, typename BT, typename CT>
__global__ __launch_bounds__(256) void gemm_bt(const AT* __restrict__ A,
                                               const BT* __restrict__ B,
                                               CT* __restrict__ C,
                                               int M, int N, int K) {
    __shared__ __align__(16) bf16 As[128 * 32];
    __shared__ __align__(16) bf16 Bs[128 * 32];
    const int tid  = threadIdx.x;
    const int wave = tid >> 6, lane = tid & 63;
    const int quad = lane >> 4, l16 = lane & 15;
    const int m0 = blockIdx.y * 128, n0 = blockIdx.x * 128;
    const int wr = (wave >> 1) * 64, wc = (wave & 1) * 64;

    // staging map: lane -> row = wave*32 + {0,16} + (lane>>2), col = (lane&3)*8
    const int srow = wave * 32 + (lane >> 2);
    const int scol = (lane & 3) * 8;
    const AT* Ag = A + (size_t)(m0 + srow) * K + scol;
    const BT* Bg = B + (size_t)(n0 + srow) * K + scol;
    bf16* Asw = &As[srow * 32 + scol];
    bf16* Bsw = &Bs[srow * 32 + scol];

    f32x4 acc[4][4] = {};

    for (int k0 = 0; k0 < K; k0 += 32) {
        const bf16x8 av0 = load8(Ag + k0);
        const bf16x8 av1 = load8(Ag + k0 + (size_t)16 * K);
        const bf16x8 bv0 = load8(Bg + k0);
        const bf16x8 bv1 = load8(Bg + k0 + (size_t)16 * K);
        __syncthreads();  // prior iteration's LDS reads complete
        *(bf16x8*)(Asw)           = av0;
        *(bf16x8*)(Asw + 16 * 32) = av1;
        *(bf16x8*)(Bsw)           = bv0;
        *(bf16x8*)(Bsw + 16 * 32) = bv1;
        __syncthreads();  // staging visible to all waves

        bf16x8 a[4], b[4];
#pragma unroll
        for (int i = 0; i < 4; ++i)
            a[i] = *(const bf16x8*)&As[(wr + i * 16 + l16) * 32 + quad * 8];
#pragma unroll
        for (int j = 0; j < 4; ++j)
            b[j] = *(const bf16x8*)&Bs[(wc + j * 16 + l16) * 32 + quad * 8];
#pragma unroll
        for (int i = 0; i < 4; ++i)
#pragma unroll
            for (int j = 0; j < 4; ++j)
                acc[i][j] = __builtin_amdgcn_mfma_f32_16x16x32_bf16(a[i], b[j], acc[i][j], 0, 0, 0);
    }

    // C/D layout: col = lane&15, row = quad*4 + reg
#pragma unroll
    for (int i = 0; i < 4; ++i)
#pragma unroll
        for (int j = 0; j < 4; ++j) {
            const int row = m0 + wr + i * 16 + quad * 4;
            const int col = n0 + wc + j * 16 + l16;
#pragma unroll
            for (int r = 0; r < 4; ++r)
                C[(size_t)(row + r) * N + col] = (CT)acc[i][j][r];
        }
}

// ---------------------------------------------------------------------------
// RMSNorm (mean-square over 256) + RoPE (theta=1e6, half=128), in place on a
// bf16 internal buffer; fp32 weights. pos = (row / div) % L.
// ---------------------------------------------------------------------------
__global__ __launch_bounds__(256) void norm_rope(bf16* __restrict__ x,
                                                 const float* __restrict__ w,
                                                 int L, int div) {
    const int row = blockIdx.x;
    const int t = threadIdx.x;
    const size_t base = (size_t)row * 256;

    const float v = (float)x[base + t];
    float ss = v * v;
#pragma unroll
    for (int off = 32; off >= 1; off >>= 1) ss += __shfl_xor(ss, off);

    __shared__ float wsum[4];
    __shared__ float buf[256];
    const int wave = t >> 6, lane = t & 63;
    if (lane == 0) wsum[wave] = ss;
    __syncthreads();
    const float var = (wsum[0] + wsum[1] + wsum[2] + wsum[3]) * (1.0f / 256.0f);
    const float inv = rsqrtf(var + 1e-6f);
    buf[t] = v * inv * w[t];
    __syncthreads();

    const int pos = (row / div) % L;
    const int i = t & 127;
    // inv_freq = 1e6 ^ (-i/128) = exp2(-i/128 * log2(1e6))
    const float freq = (float)pos * exp2f(-(float)i * (19.93156857f / 128.0f));
    const float c = cosf(freq), s = sinf(freq);
    const float x1 = buf[i], x2 = buf[i + 128];
    const float out = (t < 128) ? (x1 * c - x2 * s) : (x1 * s + x2 * c);
    x[base + t] = (bf16)out;
}

// ---------------------------------------------------------------------------
// Brute-force scalar attention, one wave per (q-row, head).
// Internal bf16 buffers; fp32 online softmax.
// Q:(B,L,H,HD) K:(B,L,HD) V:(B,L,HD) -> Ctx:(B,L,H,HD)
// ---------------------------------------------------------------------------
__global__ __launch_bounds__(256) void attn_scalar(const bf16* __restrict__ Q,
                                                   const bf16* __restrict__ K,
                                                   const bf16* __restrict__ V,
                                                   bf16* __restrict__ Ctx, int L) {
    constexpr int H = 8, HD = 256;
    const int b = blockIdx.z, h = blockIdx.y;
    const int wave = threadIdx.x >> 6, lane = threadIdx.x & 63;
    const int qr = blockIdx.x * 4 + wave;

    const bf16* qp = Q + ((size_t)(b * L + qr) * H + h) * HD + lane * 4;
    const float q0 = (float)qp[0], q1 = (float)qp[1];
    const float q2 = (float)qp[2], q3 = (float)qp[3];

    float m = -1e30f, l = 0.0f;
    float a0 = 0.f, a1 = 0.f, a2 = 0.f, a3 = 0.f;

    const bf16* Kb = K + (size_t)b * L * HD + lane * 4;
    const bf16* Vb = V + (size_t)b * L * HD + lane * 4;

    for (int j = 0; j <= qr; ++j) {
        const bf16* kp = Kb + (size_t)j * HD;
        float s = q0 * (float)kp[0] + q1 * (float)kp[1] +
                  q2 * (float)kp[2] + q3 * (float)kp[3];
#pragma unroll
        for (int off = 32; off >= 1; off >>= 1) s += __shfl_xor(s, off);
        s *= 0.0625f;  // 1/sqrt(256)

        const float mn = fmaxf(m, s);
        const float c = __expf(m - mn);
        const float p = __expf(s - mn);
        m = mn;
        l = l * c + p;

        const bf16* vp = Vb + (size_t)j * HD;
        a0 = a0 * c + p * (float)vp[0];
        a1 = a1 * c + p * (float)vp[1];
        a2 = a2 * c + p * (float)vp[2];
        a3 = a3 * c + p * (float)vp[3];
    }

    bf16* op = Ctx + ((size_t)(b * L + qr) * H + h) * HD + lane * 4;
    op[0] = (bf16)(a0 / l);
    op[1] = (bf16)(a1 / l);
    op[2] = (bf16)(a2 / l);
    op[3] = (bf16)(a3 / l);
}

// ---------------------------------------------------------------------------
extern "C" void kernel_launch(void* const* d_in, const int* in_sizes, int n_in,
                              void* d_out, int out_size, void* d_ws, size_t ws_size,
                              hipStream_t stream) {
    const float* x      = (const float*)d_in[0];
    const float* q_proj = (const float*)d_in[1];
    const float* k_proj = (const float*)d_in[2];
    const float* v_proj = (const float*)d_in[3];
    const float* o_proj = (const float*)d_in[4];
    const float* q_norm = (const float*)d_in[5];
    const float* k_norm = (const float*)d_in[6];
    float* out = (float*)d_out;  // reference output dtype is float32

    constexpr int B = 2, L = 2048, D = 2048, H = 8, HD = 256;
    constexpr int M = B * L;  // 4096

    bf16* Qw  = (bf16*)d_ws;                 // M * D      (B,L,H,HD)
    bf16* Kw  = Qw  + (size_t)M * D;         // M * HD     (B,L,HD)
    bf16* Vw  = Kw  + (size_t)M * HD;        // M * HD
    bf16* Ctx = Vw  + (size_t)M * HD;        // M * D

    // projections (fp32 in -> bf16 internal)
    gemm_bt<float, float, bf16><<<dim3(D / 128, M / 128), 256, 0, stream>>>(x, q_proj, Qw, M, D, D);
    gemm_bt<float, float, bf16><<<dim3(HD / 128, M / 128), 256, 0, stream>>>(x, k_proj, Kw, M, HD, D);
    gemm_bt<float, float, bf16><<<dim3(HD / 128, M / 128), 256, 0, stream>>>(x, v_proj, Vw, M, HD, D);
    // norm + rope (in place on internal bf16 buffers)
    norm_rope<<<M * H, 256, 0, stream>>>(Qw, q_norm, L, H);
    norm_rope<<<M, 256, 0, stream>>>(Kw, k_norm, L, 1);
    // brute-force causal MQA attention
    attn_scalar<<<dim3(L / 4, H, B), 256, 0, stream>>>(Qw, Kw, Vw, Ctx, L);
    // output projection (bf16 internal x fp32 weights -> fp32 out)
    gemm_bt<bf16, float, float><<<dim3(D / 128, M / 128), 256, 0, stream>>>(Ctx, o_proj, out, M, D, D);
}

// Round 8
// 1000.508 us; speedup vs baseline: 3.2419x; 3.2419x over previous
//
#include <hip/hip_runtime.h>
#include <hip/hip_bf16.h>
#include <stdint.h>

typedef __bf16 bf16;
typedef bf16 bf16x8 __attribute__((ext_vector_type(8)));
typedef float f32x4 __attribute__((ext_vector_type(4)));

// Load 8 consecutive elements as a bf16x8 MFMA operand pack.
__device__ __forceinline__ bf16x8 load8(const float* p) {
    const f32x4 lo = *(const f32x4*)p;
    const f32x4 hi = *(const f32x4*)(p + 4);
    bf16x8 v;
#pragma unroll
    for (int r = 0; r < 4; ++r) { v[r] = (bf16)lo[r]; v[4 + r] = (bf16)hi[r]; }
    return v;
}
__device__ __forceinline__ bf16x8 load8(const bf16* p) {
    return *(const bf16x8*)p;
}

// ---------------------------------------------------------------------------
// C[M,N] = A[M,K] @ B[N,K]^T   (fp32 accum; AT/BT in {float,bf16}; CT out)
// 128x128 tile, BK=32, 4 waves, each wave 64x64 (4x4 MFMAs). Register staging.
// (MFMA path validated: bit-matched naive fp32 GEMM in round-6 bisect.)
// ---------------------------------------------------------------------------
template <typename AT, typename BT, typename CT>
__global__ __launch_bounds__(256) void gemm_bt(const AT* __restrict__ A,
                                               const BT* __restrict__ B,
                                               CT* __restrict__ C,
                                               int M, int N, int K) {
    __shared__ __align__(16) bf16 As[128 * 32];
    __shared__ __align__(16) bf16 Bs[128 * 32];
    const int tid  = threadIdx.x;
    const int wave = tid >> 6, lane = tid & 63;
    const int quad = lane >> 4, l16 = lane & 15;
    const int m0 = blockIdx.y * 128, n0 = blockIdx.x * 128;
    const int wr = (wave >> 1) * 64, wc = (wave & 1) * 64;

    // staging map: lane -> row = wave*32 + {0,16} + (lane>>2), col = (lane&3)*8
    const int srow = wave * 32 + (lane >> 2);
    const int scol = (lane & 3) * 8;
    const AT* Ag = A + (size_t)(m0 + srow) * K + scol;
    const BT* Bg = B + (size_t)(n0 + srow) * K + scol;
    bf16* Asw = &As[srow * 32 + scol];
    bf16* Bsw = &Bs[srow * 32 + scol];

    f32x4 acc[4][4] = {};

    for (int k0 = 0; k0 < K; k0 += 32) {
        const bf16x8 av0 = load8(Ag + k0);
        const bf16x8 av1 = load8(Ag + k0 + (size_t)16 * K);
        const bf16x8 bv0 = load8(Bg + k0);
        const bf16x8 bv1 = load8(Bg + k0 + (size_t)16 * K);
        __syncthreads();  // prior iteration's LDS reads complete
        *(bf16x8*)(Asw)           = av0;
        *(bf16x8*)(Asw + 16 * 32) = av1;
        *(bf16x8*)(Bsw)           = bv0;
        *(bf16x8*)(Bsw + 16 * 32) = bv1;
        __syncthreads();  // staging visible to all waves

        bf16x8 a[4], b[4];
#pragma unroll
        for (int i = 0; i < 4; ++i)
            a[i] = *(const bf16x8*)&As[(wr + i * 16 + l16) * 32 + quad * 8];
#pragma unroll
        for (int j = 0; j < 4; ++j)
            b[j] = *(const bf16x8*)&Bs[(wc + j * 16 + l16) * 32 + quad * 8];
#pragma unroll
        for (int i = 0; i < 4; ++i)
#pragma unroll
            for (int j = 0; j < 4; ++j)
                acc[i][j] = __builtin_amdgcn_mfma_f32_16x16x32_bf16(a[i], b[j], acc[i][j], 0, 0, 0);
    }

    // C/D layout: col = lane&15, row = quad*4 + reg
#pragma unroll
    for (int i = 0; i < 4; ++i)
#pragma unroll
        for (int j = 0; j < 4; ++j) {
            const int row = m0 + wr + i * 16 + quad * 4;
            const int col = n0 + wc + j * 16 + l16;
#pragma unroll
            for (int r = 0; r < 4; ++r)
                C[(size_t)(row + r) * N + col] = (CT)acc[i][j][r];
        }
}

// ---------------------------------------------------------------------------
// RMSNorm (mean-square over 256) + RoPE (theta=1e6, half=128), in place on a
// bf16 internal buffer; fp32 weights. pos = (row / div) % L.
// ---------------------------------------------------------------------------
__global__ __launch_bounds__(256) void norm_rope(bf16* __restrict__ x,
                                                 const float* __restrict__ w,
                                                 int L, int div) {
    const int row = blockIdx.x;
    const int t = threadIdx.x;
    const size_t base = (size_t)row * 256;

    const float v = (float)x[base + t];
    float ss = v * v;
#pragma unroll
    for (int off = 32; off >= 1; off >>= 1) ss += __shfl_xor(ss, off);

    __shared__ float wsum[4];
    __shared__ float buf[256];
    const int wave = t >> 6, lane = t & 63;
    if (lane == 0) wsum[wave] = ss;
    __syncthreads();
    const float var = (wsum[0] + wsum[1] + wsum[2] + wsum[3]) * (1.0f / 256.0f);
    const float inv = rsqrtf(var + 1e-6f);
    buf[t] = v * inv * w[t];
    __syncthreads();

    const int pos = (row / div) % L;
    const int i = t & 127;
    // inv_freq = 1e6 ^ (-i/128) = exp2(-i/128 * log2(1e6))
    const float freq = (float)pos * exp2f(-(float)i * (19.93156857f / 128.0f));
    const float c = cosf(freq), s = sinf(freq);
    const float x1 = buf[i], x2 = buf[i + 128];
    const float out = (t < 128) ? (x1 * c - x2 * s) : (x1 * s + x2 * c);
    x[base + t] = (bf16)out;
}

// ---------------------------------------------------------------------------
// Vt[b][d][l] = V[b][l][d]   (key-contiguous PV B-operand loads)
// ---------------------------------------------------------------------------
__global__ __launch_bounds__(256) void transpose_v(const bf16* __restrict__ V,
                                                   bf16* __restrict__ Vt, int L) {
    __shared__ bf16 tile[32][33];
    const int b = blockIdx.z;
    const int l0 = blockIdx.x * 32, d0 = blockIdx.y * 32;
    const int tx = threadIdx.x & 31, ty = threadIdx.x >> 5;  // 32 x 8
#pragma unroll
    for (int i = 0; i < 32; i += 8)
        tile[ty + i][tx] = V[((size_t)b * L + l0 + ty + i) * 256 + d0 + tx];
    __syncthreads();
#pragma unroll
    for (int i = 0; i < 32; i += 8)
        Vt[((size_t)b * 256 + d0 + ty + i) * L + l0 + tx] = tile[tx][ty + i];
}

// ---------------------------------------------------------------------------
// Causal MQA flash attention. Q:(B,L,H,HD) K:(B,L,HD) Vt:(B,HD,L) -> Ctx:(B,L,H,HD)
// Block = 64 q rows (16/wave), KV tile = 64. No inter-wave sync.
// Q frags in registers; K/V frags straight from global (L2-resident, 8 heads reuse).
// P: C-layout -> A-layout via per-wave padded LDS (stride 72 bf16).
// Fragment maps HW-validated via round-6 GEMM bisect (same packs as gemm_bt).
// ---------------------------------------------------------------------------
__global__ __launch_bounds__(256) void flash_attn(const bf16* __restrict__ Q,
                                                  const bf16* __restrict__ K,
                                                  const bf16* __restrict__ Vt,
                                                  bf16* __restrict__ Ctx, int L) {
    constexpr int H = 8, HD = 256;
    const int qt = blockIdx.x, h = blockIdx.y, b = blockIdx.z;
    const int wave = threadIdx.x >> 6, lane = threadIdx.x & 63;
    const int quad = lane >> 4, l16 = lane & 15;
    const int q0 = qt * 64 + wave * 16;  // wave's first q row

    __shared__ bf16 Ps[4][16][72];

    // Q fragments: A-operand layout A[m=lane&15][k=quad*8+j], k-chunks of 32
    bf16x8 qf[8];
    {
        const bf16* qbase = Q + ((size_t)(b * L + q0 + l16) * H + h) * HD + quad * 8;
#pragma unroll
        for (int kc = 0; kc < 8; ++kc) qf[kc] = *(const bf16x8*)(qbase + kc * 32);
    }

    f32x4 Oacc[16] = {};
    float mrow[4], lrow[4];
#pragma unroll
    for (int r = 0; r < 4; ++r) { mrow[r] = -1e30f; lrow[r] = 0.0f; }

    const bf16* Kb = K + (size_t)b * L * HD;
    const bf16* Vb = Vt + (size_t)b * HD * L;

    for (int kt = 0; kt <= qt; ++kt) {
        const int kv0 = kt * 64;

        // ---- S = (Q K^T) : 4 key n-tiles x 8 k-chunks ----
        f32x4 S[4];
#pragma unroll
        for (int nt = 0; nt < 4; ++nt) {
            f32x4 s = {0.f, 0.f, 0.f, 0.f};
            const bf16* kbase = Kb + (size_t)(kv0 + nt * 16 + l16) * HD + quad * 8;
#pragma unroll
            for (int kc = 0; kc < 8; ++kc) {
                bf16x8 kf = *(const bf16x8*)(kbase + kc * 32);
                s = __builtin_amdgcn_mfma_f32_16x16x32_bf16(qf[kc], kf, s, 0, 0, 0);
            }
            S[nt] = s;
        }

        // ---- scale + causal mask (diag tile only) + row max ----
        float rowmax[4] = {-1e30f, -1e30f, -1e30f, -1e30f};
        const bool diag = (kt == qt);
#pragma unroll
        for (int nt = 0; nt < 4; ++nt) {
            const int col = kv0 + nt * 16 + l16;
#pragma unroll
            for (int r = 0; r < 4; ++r) {
                float sv = S[nt][r] * 0.0625f;  // 1/sqrt(256)
                if (diag && col > q0 + quad * 4 + r) sv = -1e30f;
                S[nt][r] = sv;
                rowmax[r] = fmaxf(rowmax[r], sv);
            }
        }
#pragma unroll
        for (int off = 1; off < 16; off <<= 1)
#pragma unroll
            for (int r = 0; r < 4; ++r)
                rowmax[r] = fmaxf(rowmax[r], __shfl_xor(rowmax[r], off));

        // ---- online softmax ----
        float alpha[4], rsum[4];
#pragma unroll
        for (int r = 0; r < 4; ++r) {
            const float mnew = fmaxf(mrow[r], rowmax[r]);
            alpha[r] = __expf(mrow[r] - mnew);
            mrow[r] = mnew;
            rsum[r] = 0.0f;
        }
#pragma unroll
        for (int nt = 0; nt < 4; ++nt)
#pragma unroll
            for (int r = 0; r < 4; ++r) {
                const float p = __expf(S[nt][r] - mrow[r]);
                rsum[r] += p;
                Ps[wave][quad * 4 + r][nt * 16 + l16] = (bf16)p;  // C-layout write
            }
#pragma unroll
        for (int off = 1; off < 16; off <<= 1)
#pragma unroll
            for (int r = 0; r < 4; ++r) rsum[r] += __shfl_xor(rsum[r], off);
#pragma unroll
        for (int r = 0; r < 4; ++r) lrow[r] = lrow[r] * alpha[r] + rsum[r];

        // ---- rescale O, then O += P V ----
#pragma unroll
        for (int nt = 0; nt < 16; ++nt)
#pragma unroll
            for (int r = 0; r < 4; ++r) Oacc[nt][r] *= alpha[r];

        bf16x8 pf[2];  // A-layout read of P (same wave; in-order DS + lgkmcnt)
#pragma unroll
        for (int ks = 0; ks < 2; ++ks)
            pf[ks] = *(const bf16x8*)&Ps[wave][l16][ks * 32 + quad * 8];
#pragma unroll
        for (int nt = 0; nt < 16; ++nt) {
            const bf16* vbase = Vb + (size_t)(nt * 16 + l16) * L + kv0 + quad * 8;
            f32x4 o = Oacc[nt];
#pragma unroll
            for (int ks = 0; ks < 2; ++ks) {
                bf16x8 vf = *(const bf16x8*)(vbase + ks * 32);
                o = __builtin_amdgcn_mfma_f32_16x16x32_bf16(pf[ks], vf, o, 0, 0, 0);
            }
            Oacc[nt] = o;
        }
    }

    // ---- epilogue: /l, store to Ctx (B,L,H,HD) ----
    bf16* obase = Ctx + ((size_t)(b * L + q0) * H + h) * HD;
#pragma unroll
    for (int nt = 0; nt < 16; ++nt)
#pragma unroll
        for (int r = 0; r < 4; ++r) {
            const float val = Oacc[nt][r] / lrow[r];
            obase[(size_t)(quad * 4 + r) * (H * HD) + nt * 16 + l16] = (bf16)val;
        }
}

// ---------------------------------------------------------------------------
extern "C" void kernel_launch(void* const* d_in, const int* in_sizes, int n_in,
                              void* d_out, int out_size, void* d_ws, size_t ws_size,
                              hipStream_t stream) {
    const float* x      = (const float*)d_in[0];
    const float* q_proj = (const float*)d_in[1];
    const float* k_proj = (const float*)d_in[2];
    const float* v_proj = (const float*)d_in[3];
    const float* o_proj = (const float*)d_in[4];
    const float* q_norm = (const float*)d_in[5];
    const float* k_norm = (const float*)d_in[6];
    float* out = (float*)d_out;  // reference output dtype is float32

    constexpr int B = 2, L = 2048, D = 2048, H = 8, HD = 256;
    constexpr int M = B * L;  // 4096

    bf16* Qw  = (bf16*)d_ws;                 // M * D      (B,L,H,HD)
    bf16* Kw  = Qw  + (size_t)M * D;         // M * HD     (B,L,HD)
    bf16* Vw  = Kw  + (size_t)M * HD;        // M * HD
    bf16* Vtw = Vw  + (size_t)M * HD;        // B * HD * L
    bf16* Ctx = Vtw + (size_t)M * HD;        // M * D

    // projections (fp32 in -> bf16 internal)
    gemm_bt<float, float, bf16><<<dim3(D / 128, M / 128), 256, 0, stream>>>(x, q_proj, Qw, M, D, D);
    gemm_bt<float, float, bf16><<<dim3(HD / 128, M / 128), 256, 0, stream>>>(x, k_proj, Kw, M, HD, D);
    gemm_bt<float, float, bf16><<<dim3(HD / 128, M / 128), 256, 0, stream>>>(x, v_proj, Vw, M, HD, D);
    // norm + rope (in place on internal bf16 buffers)
    norm_rope<<<M * H, 256, 0, stream>>>(Qw, q_norm, L, H);
    norm_rope<<<M, 256, 0, stream>>>(Kw, k_norm, L, 1);
    // V transpose for PV operand layout
    transpose_v<<<dim3(L / 32, HD / 32, B), 256, 0, stream>>>(Vw, Vtw, L);
    // causal MQA flash attention (MFMA)
    flash_attn<<<dim3(L / 64, H, B), 256, 0, stream>>>(Qw, Kw, Vtw, Ctx, L);
    // output projection (bf16 internal x fp32 weights -> fp32 out)
    gemm_bt<bf16, float, float><<<dim3(D / 128, M / 128), 256, 0, stream>>>(Ctx, o_proj, out, M, D, D);
}

// Round 9
// 548.580 us; speedup vs baseline: 5.9127x; 1.8238x over previous
//
#include <hip/hip_runtime.h>
#include <hip/hip_bf16.h>
#include <stdint.h>

typedef __bf16 bf16;
typedef bf16 bf16x8 __attribute__((ext_vector_type(8)));
typedef float f32x4 __attribute__((ext_vector_type(4)));

// Load 8 consecutive elements as a bf16x8 MFMA operand pack.
__device__ __forceinline__ bf16x8 load8(const float* p) {
    const f32x4 lo = *(const f32x4*)p;
    const f32x4 hi = *(const f32x4*)(p + 4);
    bf16x8 v;
#pragma unroll
    for (int r = 0; r < 4; ++r) { v[r] = (bf16)lo[r]; v[4 + r] = (bf16)hi[r]; }
    return v;
}
__device__ __forceinline__ bf16x8 load8(const bf16* p) {
    return *(const bf16x8*)p;
}

// ---------------------------------------------------------------------------
// C[M,N] = A[M,K] @ B[N,K]^T   (fp32 accum; AT/BT in {float,bf16}; CT out)
// 128x128 tile, BK=32, 4 waves, each wave 64x64 (4x4 MFMAs). Register staging.
// ---------------------------------------------------------------------------
template <typename AT, typename BT, typename CT>
__global__ __launch_bounds__(256) void gemm_bt(const AT* __restrict__ A,
                                               const BT* __restrict__ B,
                                               CT* __restrict__ C,
                                               int M, int N, int K) {
    __shared__ __align__(16) bf16 As[128 * 32];
    __shared__ __align__(16) bf16 Bs[128 * 32];
    const int tid  = threadIdx.x;
    const int wave = tid >> 6, lane = tid & 63;
    const int quad = lane >> 4, l16 = lane & 15;
    const int m0 = blockIdx.y * 128, n0 = blockIdx.x * 128;
    const int wr = (wave >> 1) * 64, wc = (wave & 1) * 64;

    const int srow = wave * 32 + (lane >> 2);
    const int scol = (lane & 3) * 8;
    const AT* Ag = A + (size_t)(m0 + srow) * K + scol;
    const BT* Bg = B + (size_t)(n0 + srow) * K + scol;
    bf16* Asw = &As[srow * 32 + scol];
    bf16* Bsw = &Bs[srow * 32 + scol];

    f32x4 acc[4][4] = {};

    for (int k0 = 0; k0 < K; k0 += 32) {
        const bf16x8 av0 = load8(Ag + k0);
        const bf16x8 av1 = load8(Ag + k0 + (size_t)16 * K);
        const bf16x8 bv0 = load8(Bg + k0);
        const bf16x8 bv1 = load8(Bg + k0 + (size_t)16 * K);
        __syncthreads();
        *(bf16x8*)(Asw)           = av0;
        *(bf16x8*)(Asw + 16 * 32) = av1;
        *(bf16x8*)(Bsw)           = bv0;
        *(bf16x8*)(Bsw + 16 * 32) = bv1;
        __syncthreads();

        bf16x8 a[4], b[4];
#pragma unroll
        for (int i = 0; i < 4; ++i)
            a[i] = *(const bf16x8*)&As[(wr + i * 16 + l16) * 32 + quad * 8];
#pragma unroll
        for (int j = 0; j < 4; ++j)
            b[j] = *(const bf16x8*)&Bs[(wc + j * 16 + l16) * 32 + quad * 8];
#pragma unroll
        for (int i = 0; i < 4; ++i)
#pragma unroll
            for (int j = 0; j < 4; ++j)
                acc[i][j] = __builtin_amdgcn_mfma_f32_16x16x32_bf16(a[i], b[j], acc[i][j], 0, 0, 0);
    }

#pragma unroll
    for (int i = 0; i < 4; ++i)
#pragma unroll
        for (int j = 0; j < 4; ++j) {
            const int row = m0 + wr + i * 16 + quad * 4;
            const int col = n0 + wc + j * 16 + l16;
#pragma unroll
            for (int r = 0; r < 4; ++r)
                C[(size_t)(row + r) * N + col] = (CT)acc[i][j][r];
        }
}

// ---------------------------------------------------------------------------
// RMSNorm + RoPE (theta=1e6, half=128), in place on bf16; fp32 weights.
// ---------------------------------------------------------------------------
__global__ __launch_bounds__(256) void norm_rope(bf16* __restrict__ x,
                                                 const float* __restrict__ w,
                                                 int L, int div) {
    const int row = blockIdx.x;
    const int t = threadIdx.x;
    const size_t base = (size_t)row * 256;

    const float v = (float)x[base + t];
    float ss = v * v;
#pragma unroll
    for (int off = 32; off >= 1; off >>= 1) ss += __shfl_xor(ss, off);

    __shared__ float wsum[4];
    __shared__ float buf[256];
    const int wave = t >> 6, lane = t & 63;
    if (lane == 0) wsum[wave] = ss;
    __syncthreads();
    const float var = (wsum[0] + wsum[1] + wsum[2] + wsum[3]) * (1.0f / 256.0f);
    const float inv = rsqrtf(var + 1e-6f);
    buf[t] = v * inv * w[t];
    __syncthreads();

    const int pos = (row / div) % L;
    const int i = t & 127;
    const float freq = (float)pos * exp2f(-(float)i * (19.93156857f / 128.0f));
    const float c = cosf(freq), s = sinf(freq);
    const float x1 = buf[i], x2 = buf[i + 128];
    const float out = (t < 128) ? (x1 * c - x2 * s) : (x1 * s + x2 * c);
    x[base + t] = (bf16)out;
}

// ---------------------------------------------------------------------------
// Vt[b][d][l] = V[b][l][d]
// ---------------------------------------------------------------------------
__global__ __launch_bounds__(256) void transpose_v(const bf16* __restrict__ V,
                                                   bf16* __restrict__ Vt, int L) {
    __shared__ bf16 tile[32][33];
    const int b = blockIdx.z;
    const int l0 = blockIdx.x * 32, d0 = blockIdx.y * 32;
    const int tx = threadIdx.x & 31, ty = threadIdx.x >> 5;
#pragma unroll
    for (int i = 0; i < 32; i += 8)
        tile[ty + i][tx] = V[((size_t)b * L + l0 + ty + i) * 256 + d0 + tx];
    __syncthreads();
#pragma unroll
    for (int i = 0; i < 32; i += 8)
        Vt[((size_t)b * 256 + d0 + ty + i) * L + l0 + tx] = tile[tx][ty + i];
}

// ---------------------------------------------------------------------------
// Causal MQA flash attention, v2.
// - Block z handles q-tiles {nqt-1-z, z}: every block = exactly nqt+1 KV steps.
// - K-tile (64x256) and Vt-tile (256x64) cooperatively staged in LDS (padded
//   strides 264/72 -> ~2-way banks), register-prefetched one tile ahead
//   (gemm_bt 2-barrier structure): one vmcnt drain per tile.
// - LDS 79,872 B dynamic -> 2 blocks/CU.
// ---------------------------------------------------------------------------
__global__ __launch_bounds__(256) void flash_attn(const bf16* __restrict__ Q,
                                                  const bf16* __restrict__ K,
                                                  const bf16* __restrict__ Vt,
                                                  bf16* __restrict__ Ctx, int L) {
    constexpr int H = 8, HD = 256;
    constexpr int KSTR = 264, VSTR = 72, PSTR = 72;
    extern __shared__ __align__(16) bf16 smem[];
    bf16* Ks = smem;                    // 64 rows x KSTR
    bf16* Vs = Ks + 64 * KSTR;          // 256 rows x VSTR
    bf16* Ps = Vs + 256 * VSTR;         // 4 waves x 16 x PSTR

    const int z = blockIdx.x, h = blockIdx.y, b = blockIdx.z;
    const int tid = threadIdx.x;
    const int wave = tid >> 6, lane = tid & 63;
    const int quad = lane >> 4, l16 = lane & 15;
    const int nqt = L / 64;

    const bf16* Kb = K + (size_t)b * L * HD;
    const bf16* Vb = Vt + (size_t)b * HD * L;
    bf16* Pw = Ps + wave * 16 * PSTR;

    // cooperative staging maps (per round i: K rows i*8+.., V rows i*32+..)
    const int krow = tid >> 5, kcol = (tid & 31) * 8;
    const int vrow = tid >> 3, vcol = (tid & 7) * 8;

    for (int pass = 0; pass < 2; ++pass) {
        const int qt = pass ? z : (nqt - 1 - z);
        const int q0 = qt * 64 + wave * 16;

        // Q fragments: A-operand layout A[m=l16][k=quad*8+j], k-chunks of 32
        bf16x8 qf[8];
        {
            const bf16* qbase = Q + ((size_t)(b * L + q0 + l16) * H + h) * HD + quad * 8;
#pragma unroll
            for (int kc = 0; kc < 8; ++kc) qf[kc] = *(const bf16x8*)(qbase + kc * 32);
        }

        f32x4 Oacc[16] = {};
        float mrow[4], lrow[4];
#pragma unroll
        for (int r = 0; r < 4; ++r) { mrow[r] = -1e30f; lrow[r] = 0.0f; }

        bf16x8 kreg[8], vreg[8];
        // prologue: stage tile 0 (all waves have passed the previous pass's
        // final post-compute barrier, so LDS reuse here is safe)
#pragma unroll
        for (int i = 0; i < 8; ++i)
            kreg[i] = *(const bf16x8*)(Kb + (size_t)(i * 8 + krow) * HD + kcol);
#pragma unroll
        for (int i = 0; i < 8; ++i)
            vreg[i] = *(const bf16x8*)(Vb + (size_t)(i * 32 + vrow) * L + vcol);
#pragma unroll
        for (int i = 0; i < 8; ++i)
            *(bf16x8*)&Ks[(i * 8 + krow) * KSTR + kcol] = kreg[i];
#pragma unroll
        for (int i = 0; i < 8; ++i)
            *(bf16x8*)&Vs[(i * 32 + vrow) * VSTR + vcol] = vreg[i];
        __syncthreads();

        for (int kt = 0; kt <= qt; ++kt) {
            const int kv0 = kt * 64;
            const bool more = (kt < qt);
            if (more) {  // prefetch next tile into registers (overlaps compute)
                const int nv0 = kv0 + 64;
#pragma unroll
                for (int i = 0; i < 8; ++i)
                    kreg[i] = *(const bf16x8*)(Kb + (size_t)(nv0 + i * 8 + krow) * HD + kcol);
#pragma unroll
                for (int i = 0; i < 8; ++i)
                    vreg[i] = *(const bf16x8*)(Vb + (size_t)(i * 32 + vrow) * L + nv0 + vcol);
            }

            // ---- S = Q K^T from LDS (two independent accum chains) ----
            f32x4 S[4];
#pragma unroll
            for (int nt = 0; nt < 4; ++nt) {
                f32x4 slo = {0.f, 0.f, 0.f, 0.f}, shi = {0.f, 0.f, 0.f, 0.f};
                const bf16* kb = &Ks[(nt * 16 + l16) * KSTR + quad * 8];
#pragma unroll
                for (int kc = 0; kc < 4; ++kc)
                    slo = __builtin_amdgcn_mfma_f32_16x16x32_bf16(qf[kc], *(const bf16x8*)(kb + kc * 32), slo, 0, 0, 0);
#pragma unroll
                for (int kc = 4; kc < 8; ++kc)
                    shi = __builtin_amdgcn_mfma_f32_16x16x32_bf16(qf[kc], *(const bf16x8*)(kb + kc * 32), shi, 0, 0, 0);
                S[nt] = slo + shi;
            }

            // ---- scale + causal mask (diag tile only) + row max ----
            float rowmax[4] = {-1e30f, -1e30f, -1e30f, -1e30f};
            const bool diag = (kt == qt);
#pragma unroll
            for (int nt = 0; nt < 4; ++nt) {
                const int col = kv0 + nt * 16 + l16;
#pragma unroll
                for (int r = 0; r < 4; ++r) {
                    float sv = S[nt][r] * 0.0625f;  // 1/sqrt(256)
                    if (diag && col > q0 + quad * 4 + r) sv = -1e30f;
                    S[nt][r] = sv;
                    rowmax[r] = fmaxf(rowmax[r], sv);
                }
            }
#pragma unroll
            for (int off = 1; off < 16; off <<= 1)
#pragma unroll
                for (int r = 0; r < 4; ++r)
                    rowmax[r] = fmaxf(rowmax[r], __shfl_xor(rowmax[r], off));

            // ---- online softmax ----
            float alpha[4], rsum[4];
#pragma unroll
            for (int r = 0; r < 4; ++r) {
                const float mnew = fmaxf(mrow[r], rowmax[r]);
                alpha[r] = __expf(mrow[r] - mnew);
                mrow[r] = mnew;
                rsum[r] = 0.0f;
            }
#pragma unroll
            for (int nt = 0; nt < 4; ++nt)
#pragma unroll
                for (int r = 0; r < 4; ++r) {
                    const float p = __expf(S[nt][r] - mrow[r]);
                    rsum[r] += p;
                    Pw[(quad * 4 + r) * PSTR + nt * 16 + l16] = (bf16)p;  // C-layout
                }
#pragma unroll
            for (int off = 1; off < 16; off <<= 1)
#pragma unroll
                for (int r = 0; r < 4; ++r) rsum[r] += __shfl_xor(rsum[r], off);
#pragma unroll
            for (int r = 0; r < 4; ++r) lrow[r] = lrow[r] * alpha[r] + rsum[r];

            // ---- rescale O, then O += P V from LDS ----
#pragma unroll
            for (int nt = 0; nt < 16; ++nt)
#pragma unroll
                for (int r = 0; r < 4; ++r) Oacc[nt][r] *= alpha[r];

            bf16x8 pf[2];
#pragma unroll
            for (int ks = 0; ks < 2; ++ks)
                pf[ks] = *(const bf16x8*)&Pw[l16 * PSTR + ks * 32 + quad * 8];
#pragma unroll
            for (int nt = 0; nt < 16; ++nt) {
                const bf16* vb2 = &Vs[(nt * 16 + l16) * VSTR + quad * 8];
                f32x4 o = Oacc[nt];
#pragma unroll
                for (int ks = 0; ks < 2; ++ks)
                    o = __builtin_amdgcn_mfma_f32_16x16x32_bf16(pf[ks], *(const bf16x8*)(vb2 + ks * 32), o, 0, 0, 0);
                Oacc[nt] = o;
            }

            __syncthreads();  // all waves done reading current LDS tiles
            if (more) {
#pragma unroll
                for (int i = 0; i < 8; ++i)
                    *(bf16x8*)&Ks[(i * 8 + krow) * KSTR + kcol] = kreg[i];
#pragma unroll
                for (int i = 0; i < 8; ++i)
                    *(bf16x8*)&Vs[(i * 32 + vrow) * VSTR + vcol] = vreg[i];
                __syncthreads();  // staged tile visible
            }
        }

        // ---- epilogue: /l, store to Ctx (B,L,H*HD) ----
        bf16* obase = Ctx + ((size_t)(b * L + q0) * H + h) * HD;
#pragma unroll
        for (int nt = 0; nt < 16; ++nt)
#pragma unroll
            for (int r = 0; r < 4; ++r) {
                const float val = Oacc[nt][r] / lrow[r];
                obase[(size_t)(quad * 4 + r) * (H * HD) + nt * 16 + l16] = (bf16)val;
            }
    }
}

// ---------------------------------------------------------------------------
extern "C" void kernel_launch(void* const* d_in, const int* in_sizes, int n_in,
                              void* d_out, int out_size, void* d_ws, size_t ws_size,
                              hipStream_t stream) {
    const float* x      = (const float*)d_in[0];
    const float* q_proj = (const float*)d_in[1];
    const float* k_proj = (const float*)d_in[2];
    const float* v_proj = (const float*)d_in[3];
    const float* o_proj = (const float*)d_in[4];
    const float* q_norm = (const float*)d_in[5];
    const float* k_norm = (const float*)d_in[6];
    float* out = (float*)d_out;

    constexpr int B = 2, L = 2048, D = 2048, H = 8, HD = 256;
    constexpr int M = B * L;  // 4096
    constexpr int FLASH_LDS = (64 * 264 + 256 * 72 + 4 * 16 * 72) * 2;  // 79,872 B

    static bool attr_set = false;  // host-side once; same device work every call
    if (!attr_set) {
        (void)hipFuncSetAttribute((const void*)flash_attn,
                                  hipFuncAttributeMaxDynamicSharedMemorySize, FLASH_LDS);
        attr_set = true;
    }

    bf16* Qw  = (bf16*)d_ws;                 // M * D      (B,L,H,HD)
    bf16* Kw  = Qw  + (size_t)M * D;         // M * HD     (B,L,HD)
    bf16* Vw  = Kw  + (size_t)M * HD;        // M * HD
    bf16* Vtw = Vw  + (size_t)M * HD;        // B * HD * L
    bf16* Ctx = Vtw + (size_t)M * HD;        // M * D

    gemm_bt<float, float, bf16><<<dim3(D / 128, M / 128), 256, 0, stream>>>(x, q_proj, Qw, M, D, D);
    gemm_bt<float, float, bf16><<<dim3(HD / 128, M / 128), 256, 0, stream>>>(x, k_proj, Kw, M, HD, D);
    gemm_bt<float, float, bf16><<<dim3(HD / 128, M / 128), 256, 0, stream>>>(x, v_proj, Vw, M, HD, D);
    norm_rope<<<M * H, 256, 0, stream>>>(Qw, q_norm, L, H);
    norm_rope<<<M, 256, 0, stream>>>(Kw, k_norm, L, 1);
    transpose_v<<<dim3(L / 32, HD / 32, B), 256, 0, stream>>>(Vw, Vtw, L);
    flash_attn<<<dim3(L / 128, H, B), 256, FLASH_LDS, stream>>>(Qw, Kw, Vtw, Ctx, L);
    gemm_bt<bf16, float, float><<<dim3(D / 128, M / 128), 256, 0, stream>>>(Ctx, o_proj, out, M, D, D);
}